// Round 6
// baseline (1739.423 us; speedup 1.0000x reference)
//
#include <hip/hip_runtime.h>
#include <hip/hip_bf16.h>

namespace {

constexpr int Bb = 8;
constexpr int Lr = 512;
constexpr int Dd = 1024;
constexpr int Mm = 64;
constexpr int Tt = 8;
constexpr int BL = Bb * Lr;      // 4096
constexpr int NRP = 132;         // padded row stride for qrel (129 used)

constexpr size_t H  = (size_t)BL * Dd;        // per-stream hid elems
constexpr size_t QS = (size_t)BL * NRP;       // per-stream qrel elems
constexpr size_t SC = (size_t)Bb * Lr * Lr;   // per-stream scores elems
constexpr size_t PS = SC;                     // per-stream probs elems

constexpr int TILE = 128 * 64;                // one LDS tile (shorts)

typedef __attribute__((ext_vector_type(8))) short bf16x8;
typedef __attribute__((ext_vector_type(4))) float f32x4;

__device__ __forceinline__ short f2bf(float x) {
    __hip_bfloat16 h = __float2bfloat16(x);
    return *reinterpret_cast<short*>(&h);
}

// ---------------------------------------------------------------------------
// Core: C_tile(128x128) += A @ B^T, A/B bf16 row-major [rows x K].
// A rows use A1 for k<ksplit else A2 (k-ksplit).
// 2-phase double-buffered (T3-minimum): issue next K-tile's global_load_lds
// BEFORE ds_read+MFMA of current tile; one barrier per K-step.
// As/Bs are 2*TILE shorts each (64 KB total LDS).
// ---------------------------------------------------------------------------
__device__ __forceinline__ void gemm_core(
    const short* __restrict__ A1, const short* __restrict__ A2, int ksplit,
    int lda, const short* __restrict__ Bm, int ldb, int K,
    short* As, short* Bs, f32x4 acc[4][4])
{
    const int tid  = threadIdx.x;
    const int lane = tid & 63;
    const int w    = tid >> 6;
    const int wm   = w >> 1, wn = w & 1;
    const int lr   = lane >> 3;         // row within 8-row group
    const int lc   = (lane & 7) << 3;   // elem col: 0,8,..,56

    auto stage = [&](int k0, int buf) {
        const short* Abase = (k0 < ksplit) ? A1 : A2;
        const int kc = (k0 < ksplit) ? k0 : (k0 - ksplit);
        short* Ad = As + buf * TILE;
        short* Bd = Bs + buf * TILE;
        #pragma unroll
        for (int i = 0; i < 4; ++i) {
            const int r0 = (i * 4 + w) * 8;
            const short* gA = Abase + (size_t)(r0 + lr) * lda + kc + lc;
            __builtin_amdgcn_global_load_lds(
                (const __attribute__((address_space(1))) void*)gA,
                (__attribute__((address_space(3))) void*)(Ad + r0 * 64), 16, 0, 0);
            const short* gB = Bm + (size_t)(r0 + lr) * ldb + k0 + lc;
            __builtin_amdgcn_global_load_lds(
                (const __attribute__((address_space(1))) void*)gB,
                (__attribute__((address_space(3))) void*)(Bd + r0 * 64), 16, 0, 0);
        }
    };

    stage(0, 0);
    __syncthreads();                 // buf0 ready
    int buf = 0;
    for (int k0 = 0; k0 < K; k0 += 64) {
        if (k0 + 64 < K) stage(k0 + 64, buf ^ 1);   // prefetch next K-tile
        const short* Ab = As + buf * TILE;
        const short* Bb = Bs + buf * TILE;
        #pragma unroll
        for (int ks = 0; ks < 2; ++ks) {
            bf16x8 af[4], bb[4];
            #pragma unroll
            for (int f = 0; f < 4; ++f) {
                af[f] = *(const bf16x8*)(Ab + (wm * 64 + f * 16 + (lane & 15)) * 64
                                            + ks * 32 + ((lane >> 4) << 3));
                bb[f] = *(const bf16x8*)(Bb + (wn * 64 + f * 16 + (lane & 15)) * 64
                                            + ks * 32 + ((lane >> 4) << 3));
            }
            #pragma unroll
            for (int fm = 0; fm < 4; ++fm)
                #pragma unroll
                for (int fn = 0; fn < 4; ++fn)
                    acc[fm][fn] = __builtin_amdgcn_mfma_f32_16x16x32_bf16(
                        af[fm], bb[fn], acc[fm][fn], 0, 0, 0);
        }
        __syncthreads();             // next buf staged + all reads of buf done
        buf ^= 1;
    }
}

// Fused q/k/qrel projection, both streams. 1-D grid 18*64=1152, XCD-swizzled.
// n-tile 0-7: q (scaled), 8-15: k, 16-17: qrel via RW (fp32 out).
__global__ __launch_bounds__(256)
void proj2_k(const short* __restrict__ h0, const short* __restrict__ h1,
             const short* __restrict__ wq0, const short* __restrict__ wk0,
             const short* __restrict__ wq1, const short* __restrict__ wk1,
             const short* __restrict__ rw0, const short* __restrict__ rw1,
             const float* __restrict__ bq0, const float* __restrict__ bk0,
             const float* __restrict__ bq1, const float* __restrict__ bk1,
             const float* __restrict__ rbv,
             short* __restrict__ qout, short* __restrict__ kout,
             float* __restrict__ qrelb)
{
    __shared__ short As[2 * TILE], Bs[2 * TILE];
    f32x4 acc[4][4] = {};
    const int sid = (blockIdx.x & 7) * (1152 / 8) + (blockIdx.x >> 3);
    const int nt = sid % 18, mt = sid / 18;
    const int s  = mt >> 5;
    const int m0 = (mt & 31) * 128;
    const short* h = s ? h1 : h0;
    int kind, n0;
    const short* W;
    if (nt < 8)       { kind = 0; n0 = nt * 128;        W = s ? wq1 : wq0; }
    else if (nt < 16) { kind = 1; n0 = (nt - 8) * 128;  W = s ? wk1 : wk0; }
    else              { kind = 2; n0 = (nt - 16) * 128; W = s ? rw1 : rw0; }
    gemm_core(h + (size_t)m0 * Dd, h + (size_t)m0 * Dd, 1 << 30, Dd,
              W + (size_t)n0 * Dd, Dd, Dd, As, Bs, acc);
    const int lane = threadIdx.x & 63, w = threadIdx.x >> 6;
    const int wm = w >> 1, wn = w & 1;
    if (kind == 2) {
        const float* rbp = rbv + s * NRP;
        float* out = qrelb + (size_t)s * QS;
        #pragma unroll
        for (int fm = 0; fm < 4; ++fm)
            #pragma unroll
            for (int fn = 0; fn < 4; ++fn) {
                const int r = n0 + wn * 64 + fn * 16 + (lane & 15);
                if (r < 129) {
                    #pragma unroll
                    for (int rr = 0; rr < 4; ++rr) {
                        const int ml = wm * 64 + fm * 16 + ((lane >> 4) << 2) + rr;
                        out[(size_t)(m0 + ml) * NRP + r] =
                            0.03125f * (acc[fm][fn][rr] + rbp[r]);
                    }
                }
            }
    } else {
        const float* bias = kind == 0 ? (s ? bq1 : bq0) : (s ? bk1 : bk0);
        const float alpha = kind == 0 ? 0.03125f : 1.0f;
        short* out = (kind == 0 ? qout : kout) + (size_t)s * H;
        #pragma unroll
        for (int fm = 0; fm < 4; ++fm)
            #pragma unroll
            for (int fn = 0; fn < 4; ++fn) {
                const int nl = wn * 64 + fn * 16 + (lane & 15);
                #pragma unroll
                for (int rr = 0; rr < 4; ++rr) {
                    const int ml = wm * 64 + fm * 16 + ((lane >> 4) << 2) + rr;
                    out[(size_t)(m0 + ml) * Dd + n0 + nl] =
                        f2bf((acc[fm][fn][rr] + bias[n0 + nl]) * alpha);
                }
            }
    }
}

// scores[s,b,i,j] = q.k + qrel gather. 1-D grid 256, XCD-swizzled.
__global__ __launch_bounds__(256)
void scores2_k(const short* __restrict__ q, const short* __restrict__ kmat,
               const float* __restrict__ qrelb, float* __restrict__ scb)
{
    __shared__ short As[2 * TILE], Bs[2 * TILE];
    f32x4 acc[4][4] = {};
    const int sid = (blockIdx.x & 7) * (256 / 8) + (blockIdx.x >> 3);
    const int n0 = (sid & 3) * 128, m0 = ((sid >> 2) & 3) * 128;
    const int z = sid >> 4;
    const int s = z >> 3, b = z & 7;
    const short* A = q    + (size_t)s * H + ((size_t)b * Lr + m0) * Dd;
    const short* B = kmat + (size_t)s * H + ((size_t)b * Lr + n0) * Dd;
    const float* qr = qrelb + (size_t)s * QS;
    float* out = scb + (size_t)s * SC;
    gemm_core(A, A, 1 << 30, Dd, B, Dd, Dd, As, Bs, acc);
    const int lane = threadIdx.x & 63, w = threadIdx.x >> 6;
    const int wm = w >> 1, wn = w & 1;
    #pragma unroll
    for (int fm = 0; fm < 4; ++fm)
        #pragma unroll
        for (int fn = 0; fn < 4; ++fn) {
            const int j = n0 + wn * 64 + fn * 16 + (lane & 15);
            #pragma unroll
            for (int r = 0; r < 4; ++r) {
                const int i = m0 + wm * 64 + fm * 16 + ((lane >> 4) << 2) + r;
                int d = j - i;
                d = d < -Mm ? -Mm : (d > Mm ? Mm : d);
                out[((size_t)b * Lr + i) * Lr + j] =
                    acc[fm][fn][r] + qr[((size_t)b * Lr + i) * NRP + d + Mm];
            }
        }
}

// Masked softmax both streams: grid (512, 8, 2)
__global__ __launch_bounds__(256)
void softmax2_k(const float* __restrict__ scb, const int* __restrict__ spw,
                float* __restrict__ out0, float* __restrict__ out1,
                short* __restrict__ probs, int t)
{
    const int i = blockIdx.x, b = blockIdx.y, s = blockIdx.z;
    const float* srow = scb + (size_t)s * SC + ((size_t)b * Lr + i) * Lr;
    const int tidx = threadIdx.x;
    float s0, s1;
    {
        int w = spw[b * Lr + tidx];
        s0 = (w != 0 && t <= w) ? srow[tidx] : -1e18f;
        w = spw[b * Lr + tidx + 256];
        s1 = (w != 0 && t <= w) ? srow[tidx + 256] : -1e18f;
    }
    float mx = fmaxf(s0, s1);
    #pragma unroll
    for (int off = 32; off > 0; off >>= 1) mx = fmaxf(mx, __shfl_down(mx, off));
    __shared__ float redm[4], reds[4];
    const int lane = tidx & 63, wid = tidx >> 6;
    if (lane == 0) redm[wid] = mx;
    __syncthreads();
    mx = fmaxf(fmaxf(redm[0], redm[1]), fmaxf(redm[2], redm[3]));
    const float e0 = expf(s0 - mx), e1 = expf(s1 - mx);
    float sum = e0 + e1;
    #pragma unroll
    for (int off = 32; off > 0; off >>= 1) sum += __shfl_down(sum, off);
    if (lane == 0) reds[wid] = sum;
    __syncthreads();
    const float inv = 1.f / (reds[0] + reds[1] + reds[2] + reds[3]);
    const float p0 = e0 * inv, p1 = e1 * inv;
    float* orow = (s ? out1 : out0) + (((size_t)b * Lr + i) * Tt + t) * Lr;
    orow[tidx]       = p0;
    orow[tidx + 256] = p1;
    short* prow = probs + (size_t)s * PS + ((size_t)b * Lr + i) * Lr;
    prow[tidx]       = f2bf(p0);
    prow[tidx + 256] = f2bf(p1);
}

// hc = P @ hidT^T both streams. 1-D grid 512, XCD-swizzled.
__global__ __launch_bounds__(256)
void pv2_k(const short* __restrict__ probs,
           const short* __restrict__ hT0, const short* __restrict__ hT1,
           short* __restrict__ hc)
{
    __shared__ short As[2 * TILE], Bs[2 * TILE];
    f32x4 acc[4][4] = {};
    const int sid = (blockIdx.x & 7) * (512 / 8) + (blockIdx.x >> 3);
    const int n0 = (sid & 7) * 128, m0 = ((sid >> 3) & 3) * 128;
    const int z = sid >> 5;
    const int s = z >> 3, b = z & 7;
    const short* A = probs + (size_t)s * PS + ((size_t)b * Lr + m0) * Lr;
    const short* B = (s ? hT1 : hT0) + ((size_t)b * Dd + n0) * Lr;
    short* out = hc + (size_t)s * H;
    gemm_core(A, A, 1 << 30, Lr, B, Lr, Lr, As, Bs, acc);
    const int lane = threadIdx.x & 63, w = threadIdx.x >> 6;
    const int wm = w >> 1, wn = w & 1;
    #pragma unroll
    for (int fm = 0; fm < 4; ++fm)
        #pragma unroll
        for (int fn = 0; fn < 4; ++fn) {
            const int n = n0 + wn * 64 + fn * 16 + (lane & 15);
            #pragma unroll
            for (int r = 0; r < 4; ++r) {
                const int i = m0 + wm * 64 + fm * 16 + ((lane >> 4) << 2) + r;
                out[((size_t)b * Lr + i) * Dd + n] = f2bf(acc[fm][fn][r]);
            }
        }
}

// h' = relu(concat(h,hc) @ Wc^T + cb). 1-D grid 512, XCD-swizzled.
__global__ __launch_bounds__(256)
void comb2_k(const short* __restrict__ h0, const short* __restrict__ h1,
             const short* __restrict__ hc,
             const short* __restrict__ Wc, const float* __restrict__ cb,
             short* __restrict__ hn0, short* __restrict__ hn1,
             short* __restrict__ hT0, short* __restrict__ hT1)
{
    __shared__ short As[2 * TILE], Bs[2 * TILE];
    f32x4 acc[4][4] = {};
    const int sid = (blockIdx.x & 7) * (512 / 8) + (blockIdx.x >> 3);
    const int n0 = (sid & 7) * 128;
    const int mt = sid >> 3;
    const int s  = mt >> 5;
    const int m0 = (mt & 31) * 128;
    const short* h = s ? h1 : h0;
    gemm_core(h + (size_t)m0 * Dd,
              hc + (size_t)s * H + (size_t)m0 * Dd, Dd, Dd,
              Wc + (size_t)n0 * 2 * Dd, 2 * Dd, 2 * Dd, As, Bs, acc);
    short* hout = s ? hn1 : hn0;
    short* hT   = s ? hT1 : hT0;
    const int lane = threadIdx.x & 63, w = threadIdx.x >> 6;
    const int wm = w >> 1, wn = w & 1;
    const int b = m0 >> 9;
    const int il_base = (m0 & 511) + wm * 64 + ((lane >> 4) << 2);
    #pragma unroll
    for (int fm = 0; fm < 4; ++fm)
        #pragma unroll
        for (int fn = 0; fn < 4; ++fn) {
            const int n = n0 + wn * 64 + fn * 16 + (lane & 15);
            const float bias = cb[n];
            short4 pk;
            short* pks = reinterpret_cast<short*>(&pk);
            #pragma unroll
            for (int r = 0; r < 4; ++r) {
                const int m = m0 + wm * 64 + fm * 16 + ((lane >> 4) << 2) + r;
                const float v = fmaxf(acc[fm][fn][r] + bias, 0.f);
                const short sv = f2bf(v);
                hout[(size_t)m * Dd + n] = sv;
                pks[r] = sv;
            }
            *reinterpret_cast<short4*>(
                &hT[((size_t)b * Dd + n) * Lr + il_base + fm * 16]) = pk;
        }
}

// RW[s] = relp[s] @ wqT[s]^T  (bf16 out, 256x1024). Grid 32 blocks.
__global__ __launch_bounds__(256)
void rw_k(const short* __restrict__ relp0, const short* __restrict__ relp1,
          const short* __restrict__ wqT0, const short* __restrict__ wqT1,
          short* __restrict__ rw0, short* __restrict__ rw1)
{
    __shared__ short As[2 * TILE], Bs[2 * TILE];
    f32x4 acc[4][4] = {};
    const int sid = blockIdx.x;
    const int s = sid >> 4, rem = sid & 15;
    const int n0 = (rem & 7) * 128, m0 = (rem >> 3) * 128;
    const short* A = (s ? relp1 : relp0) + (size_t)m0 * Dd;
    const short* B = (s ? wqT1 : wqT0) + (size_t)n0 * Dd;
    short* out = s ? rw1 : rw0;
    gemm_core(A, A, 1 << 30, Dd, B, Dd, Dd, As, Bs, acc);
    const int lane = threadIdx.x & 63, w = threadIdx.x >> 6;
    const int wm = w >> 1, wn = w & 1;
    #pragma unroll
    for (int fm = 0; fm < 4; ++fm)
        #pragma unroll
        for (int fn = 0; fn < 4; ++fn) {
            const int nl = wn * 64 + fn * 16 + (lane & 15);
            #pragma unroll
            for (int r = 0; r < 4; ++r) {
                const int ml = wm * 64 + fm * 16 + ((lane >> 4) << 2) + r;
                out[(size_t)(m0 + ml) * Dd + n0 + nl] = f2bf(acc[fm][fn][r]);
            }
        }
}

// rb[s][r] = rel_s[r,:] . bq_s   grid (129,2), block 64
__global__ __launch_bounds__(64)
void rb_k(const float* __restrict__ rel0, const float* __restrict__ rel1,
          const float* __restrict__ bq0, const float* __restrict__ bq1,
          float* __restrict__ rbv)
{
    const int r = blockIdx.x, s = blockIdx.y;
    const float* rel = s ? rel1 : rel0;
    const float* bq  = s ? bq1 : bq0;
    float sum = 0.f;
    for (int n = threadIdx.x; n < Dd; n += 64)
        sum += rel[(size_t)r * Dd + n] * bq[n];
    #pragma unroll
    for (int off = 32; off > 0; off >>= 1) sum += __shfl_down(sum, off);
    if (threadIdx.x == 0) rbv[s * NRP + r] = sum;
}

// dst[e][n] = f2bf(src[n][e])  64x64 LDS tiles, grid (16,16,2)
__global__ __launch_bounds__(256)
void transpose_f2bf_k(const float* __restrict__ src0, const float* __restrict__ src1,
                      short* __restrict__ dst0, short* __restrict__ dst1)
{
    __shared__ float tile[64][65];
    const float* src = blockIdx.z ? src1 : src0;
    short* dst = blockIdx.z ? dst1 : dst0;
    const int r0 = blockIdx.y * 64, c0 = blockIdx.x * 64;
    const int col = threadIdx.x & 63, row4 = threadIdx.x >> 6;
    #pragma unroll
    for (int rr = 0; rr < 16; ++rr)
        tile[row4 + rr * 4][col] = src[(size_t)(r0 + row4 + rr * 4) * Dd + c0 + col];
    __syncthreads();
    #pragma unroll
    for (int rr = 0; rr < 16; ++rr)
        dst[(size_t)(c0 + row4 + rr * 4) * Dd + r0 + col] =
            f2bf(tile[col][row4 + rr * 4]);
}

__global__ void masks_k(const int* __restrict__ spw, float* __restrict__ out2)
{
    const int idx = blockIdx.x * 256 + threadIdx.x;
    if (idx < BL) {
        const int w = spw[idx];
        #pragma unroll
        for (int t = 0; t < Tt; ++t)
            out2[(size_t)idx * Tt + t] = (w != 0 && t <= w) ? 1.f : 0.f;
    }
}

__global__ void f2bf_k(const float* __restrict__ src, short* __restrict__ dst, int n)
{
    const int idx = blockIdx.x * 256 + threadIdx.x;
    if (idx < n) dst[idx] = f2bf(src[idx]);
}

__global__ void relpad_k(const float* __restrict__ rel, short* __restrict__ dst)
{
    const int idx = blockIdx.x * 256 + threadIdx.x;   // 256*1024 total
    if (idx < 256 * 1024) {
        const int row = idx >> 10;
        dst[idx] = (row < 129) ? f2bf(rel[idx]) : (short)0;
    }
}

__global__ void hidinit_k(const float* __restrict__ hid,
                          short* __restrict__ h_st, short* __restrict__ h_ed,
                          short* __restrict__ hT_st, short* __restrict__ hT_ed)
{
    const int idx = blockIdx.x * 256 + threadIdx.x;
    if (idx < BL * Dd) {
        const int i = idx >> 10, d = idx & 1023;
        const int b = i >> 9, il = i & 511;
        const short s = f2bf(hid[idx]);
        h_st[idx] = s;
        h_ed[idx] = s;
        hT_st[((size_t)b * Dd + d) * Lr + il] = s;
        hT_ed[((size_t)b * Dd + d) * Lr + il] = s;
    }
}

} // namespace

extern "C" void kernel_launch(void* const* d_in, const int* in_sizes, int n_in,
                              void* d_out, int out_size, void* d_ws, size_t ws_size,
                              hipStream_t stream)
{
    const float* hid  = (const float*)d_in[0];
    const int*   spw  = (const int*)d_in[1];
    const float* Wq[2] = {(const float*)d_in[2], (const float*)d_in[7]};
    const float* bq[2] = {(const float*)d_in[3], (const float*)d_in[8]};
    const float* Wk[2] = {(const float*)d_in[4], (const float*)d_in[9]};
    const float* bk[2] = {(const float*)d_in[5], (const float*)d_in[10]};
    const float* rel[2]= {(const float*)d_in[6], (const float*)d_in[11]};
    const float* combW = (const float*)d_in[12];
    const float* combB = (const float*)d_in[13];

    float* out0 = (float*)d_out;
    float* out1 = out0 + (size_t)BL * Tt * Lr;
    float* out2 = out1 + (size_t)BL * Tt * Lr;

    // ---- workspace layout ----
    short* wsS = (short*)d_ws;
    size_t cur = 0;
    short* hbuf[2][2];
    hbuf[0][0] = wsS + cur; cur += H;
    hbuf[0][1] = wsS + cur; cur += H;
    hbuf[1][0] = wsS + cur; cur += H;
    hbuf[1][1] = wsS + cur; cur += H;
    short* hidT[2];
    hidT[0] = wsS + cur; cur += H;
    hidT[1] = wsS + cur; cur += H;
    short* qb = wsS + cur; cur += 2 * H;
    short* kb = wsS + cur; cur += 2 * H;   // aliased: hc reuses kb (kb dead after scores)
    short* hc = kb;
    short* probs = wsS + cur; cur += 2 * PS;
    short* wqb[2], *wkb[2];
    wqb[0] = wsS + cur; cur += (size_t)Dd * Dd;
    wkb[0] = wsS + cur; cur += (size_t)Dd * Dd;
    wqb[1] = wsS + cur; cur += (size_t)Dd * Dd;
    wkb[1] = wsS + cur; cur += (size_t)Dd * Dd;
    short* combWb = wsS + cur; cur += (size_t)Dd * 2 * Dd;
    short* relp[2];
    relp[0] = wsS + cur; cur += (size_t)256 * Dd;
    relp[1] = wsS + cur; cur += (size_t)256 * Dd;
    short* rwb[2];
    rwb[0] = wsS + cur; cur += (size_t)256 * Dd;
    rwb[1] = wsS + cur; cur += (size_t)256 * Dd;
    float* wsF = (float*)(wsS + cur);
    float* rbv   = wsF;                          // 2*NRP
    float* qrelb = wsF + 2 * NRP;                // 2 * QS fp32
    float* scb   = qrelb + 2 * QS;               // 2 * SC fp32
    // wqT scratch aliases scb (setup-only use, scb written later)
    short* wqT[2] = {(short*)scb, (short*)scb + (size_t)Dd * Dd};

    // ---- setup ----
    const int DD = Dd * Dd;
    f2bf_k<<<dim3((DD + 255) / 256), 256, 0, stream>>>(Wq[0], wqb[0], DD);
    f2bf_k<<<dim3((DD + 255) / 256), 256, 0, stream>>>(Wk[0], wkb[0], DD);
    f2bf_k<<<dim3((DD + 255) / 256), 256, 0, stream>>>(Wq[1], wqb[1], DD);
    f2bf_k<<<dim3((DD + 255) / 256), 256, 0, stream>>>(Wk[1], wkb[1], DD);
    f2bf_k<<<dim3((2 * DD + 255) / 256), 256, 0, stream>>>(combW, combWb, 2 * DD);
    relpad_k<<<dim3(256 * Dd / 256), 256, 0, stream>>>(rel[0], relp[0]);
    relpad_k<<<dim3(256 * Dd / 256), 256, 0, stream>>>(rel[1], relp[1]);
    transpose_f2bf_k<<<dim3(16, 16, 2), 256, 0, stream>>>(Wq[0], Wq[1], wqT[0], wqT[1]);
    rw_k<<<dim3(32), 256, 0, stream>>>(relp[0], relp[1], wqT[0], wqT[1], rwb[0], rwb[1]);
    rb_k<<<dim3(129, 2), 64, 0, stream>>>(rel[0], rel[1], bq[0], bq[1], rbv);
    hidinit_k<<<dim3((int)(H / 256)), 256, 0, stream>>>(hid, hbuf[0][0], hbuf[1][0],
                                                        hidT[0], hidT[1]);
    masks_k<<<dim3((BL + 255) / 256), 256, 0, stream>>>(spw, out2);

    int curb = 0;
    for (int t = 0; t < Tt; ++t) {
        short* h0 = hbuf[0][curb], *h1 = hbuf[1][curb];
        short* hn0 = hbuf[0][curb ^ 1], *hn1 = hbuf[1][curb ^ 1];
        proj2_k<<<dim3(1152), 256, 0, stream>>>(
            h0, h1, wqb[0], wkb[0], wqb[1], wkb[1], rwb[0], rwb[1],
            bq[0], bk[0], bq[1], bk[1], rbv, qb, kb, qrelb);
        scores2_k<<<dim3(256), 256, 0, stream>>>(qb, kb, qrelb, scb);
        softmax2_k<<<dim3(Lr, Bb, 2), 256, 0, stream>>>(scb, spw, out0, out1, probs, t);
        pv2_k<<<dim3(512), 256, 0, stream>>>(probs, hidT[0], hidT[1], hc);
        comb2_k<<<dim3(512), 256, 0, stream>>>(h0, h1, hc, combWb, combB,
                                               hn0, hn1, hidT[0], hidT[1]);
        curb ^= 1;
    }
}

// Round 7
// 1505.011 us; speedup vs baseline: 1.1558x; 1.1558x over previous
//
#include <hip/hip_runtime.h>
#include <hip/hip_bf16.h>

namespace {

constexpr int Bb = 8;
constexpr int Lr = 512;
constexpr int Dd = 1024;
constexpr int Mm = 64;
constexpr int Tt = 8;
constexpr int BL = Bb * Lr;      // 4096

constexpr size_t H    = (size_t)BL * Dd;        // per-stream hid elems (4096x1024)
constexpr size_t SC   = (size_t)Bb * Lr * Lr;   // per-stream scores elems
constexpr size_t PS   = SC;                     // per-stream probs elems
constexpr size_t GSZ  = (size_t)BL * 1280;      // per-stream g elems
constexpr size_t WASZ = (size_t)1280 * Dd;      // per-stream W_aug elems

constexpr int TILE = 128 * 64;                  // one LDS tile (shorts)

typedef __attribute__((ext_vector_type(8))) short bf16x8;
typedef __attribute__((ext_vector_type(4))) float f32x4;

__device__ __forceinline__ short f2bf(float x) {
    __hip_bfloat16 h = __float2bfloat16(x);
    return *reinterpret_cast<short*>(&h);
}
__device__ __forceinline__ float bf2f(short s) {
    unsigned int u = ((unsigned int)(unsigned short)s) << 16;
    return __uint_as_float(u);
}

// ---------------------------------------------------------------------------
// Core: C_tile(128x128) += A @ B^T, A/B bf16 row-major [rows x K].
// m97 structure: BK=64, global_load_lds w16, 2 barriers/K-step, 4 waves.
// ---------------------------------------------------------------------------
__device__ __forceinline__ void gemm_core(
    const short* __restrict__ A, int lda,
    const short* __restrict__ Bm, int ldb, int K,
    short* As, short* Bs, f32x4 acc[4][4])
{
    const int tid  = threadIdx.x;
    const int lane = tid & 63;
    const int w    = tid >> 6;
    const int wm   = w >> 1, wn = w & 1;
    const int lr   = lane >> 3;         // row within 8-row group
    const int lc   = (lane & 7) << 3;   // elem col: 0,8,..,56

    for (int k0 = 0; k0 < K; k0 += 64) {
        #pragma unroll
        for (int i = 0; i < 4; ++i) {
            const int r0 = (i * 4 + w) * 8;
            const short* gA = A + (size_t)(r0 + lr) * lda + k0 + lc;
            __builtin_amdgcn_global_load_lds(
                (const __attribute__((address_space(1))) void*)gA,
                (__attribute__((address_space(3))) void*)(As + r0 * 64), 16, 0, 0);
            const short* gB = Bm + (size_t)(r0 + lr) * ldb + k0 + lc;
            __builtin_amdgcn_global_load_lds(
                (const __attribute__((address_space(1))) void*)gB,
                (__attribute__((address_space(3))) void*)(Bs + r0 * 64), 16, 0, 0);
        }
        __syncthreads();
        #pragma unroll
        for (int ks = 0; ks < 2; ++ks) {
            bf16x8 af[4], bb[4];
            #pragma unroll
            for (int f = 0; f < 4; ++f) {
                af[f] = *(const bf16x8*)(As + (wm * 64 + f * 16 + (lane & 15)) * 64
                                            + ks * 32 + ((lane >> 4) << 3));
                bb[f] = *(const bf16x8*)(Bs + (wn * 64 + f * 16 + (lane & 15)) * 64
                                            + ks * 32 + ((lane >> 4) << 3));
            }
            #pragma unroll
            for (int fm = 0; fm < 4; ++fm)
                #pragma unroll
                for (int fn = 0; fn < 4; ++fn)
                    acc[fm][fn] = __builtin_amdgcn_mfma_f32_16x16x32_bf16(
                        af[fm], bb[fn], acc[fm][fn], 0, 0, 0);
        }
        __syncthreads();
    }
}

// ---------------------------------------------------------------------------
// G-GEMM: [g | x | yT] = h @ Wtot^T, both streams.
// grid 1664 = 8 XCD chunks x (26 nt x 8 mt), nt-major within chunk so the
// 0.25 MB weight panel stays L2-hot across 8 consecutive m-tiles.
// nt 0-9: -> g (cols 0-1279: M^T 0-1023, RW 1024-1152, u 1153, v 1154, pad0)
// nt 10-17: x = h@Wc1^T ; nt 18-25: yT = (h@Wc2^T) transposed per batch.
// ---------------------------------------------------------------------------
__global__ __launch_bounds__(256)
void gg_k(const short* __restrict__ h0, const short* __restrict__ h1,
          const short* __restrict__ waug, const short* __restrict__ wc,
          short* __restrict__ g, short* __restrict__ x, short* __restrict__ yT)
{
    __shared__ short As[TILE], Bs[TILE];
    f32x4 acc[4][4] = {};
    const int xcd = blockIdx.x & 7;
    const int l   = blockIdx.x >> 3;          // 0..207
    const int nt  = l >> 3;                   // 0..25
    const int mt  = xcd * 8 + (l & 7);        // 0..63
    const int s   = mt >> 5;
    const int m0  = (mt & 31) * 128;
    const short* h = s ? h1 : h0;
    const short* Bm; int ldb;
    if (nt < 10)      { Bm = waug + (size_t)s * WASZ + (size_t)nt * 128 * Dd; ldb = Dd; }
    else if (nt < 18) { Bm = wc + (size_t)(nt - 10) * 128 * 2048;             ldb = 2048; }
    else              { Bm = wc + 1024 + (size_t)(nt - 18) * 128 * 2048;      ldb = 2048; }
    gemm_core(h + (size_t)m0 * Dd, Dd, Bm, ldb, Dd, As, Bs, acc);

    const int lane = threadIdx.x & 63, w = threadIdx.x >> 6;
    const int wm = w >> 1, wn = w & 1;
    if (nt < 10) {
        short* out = g + (size_t)s * GSZ;
        #pragma unroll
        for (int fm = 0; fm < 4; ++fm)
            #pragma unroll
            for (int fn = 0; fn < 4; ++fn) {
                const int col = nt * 128 + wn * 64 + fn * 16 + (lane & 15);
                #pragma unroll
                for (int rr = 0; rr < 4; ++rr) {
                    const int ml = wm * 64 + fm * 16 + ((lane >> 4) << 2) + rr;
                    out[(size_t)(m0 + ml) * 1280 + col] = f2bf(acc[fm][fn][rr]);
                }
            }
    } else if (nt < 18) {
        short* out = x + (size_t)s * H;
        #pragma unroll
        for (int fm = 0; fm < 4; ++fm)
            #pragma unroll
            for (int fn = 0; fn < 4; ++fn) {
                const int col = (nt - 10) * 128 + wn * 64 + fn * 16 + (lane & 15);
                #pragma unroll
                for (int rr = 0; rr < 4; ++rr) {
                    const int ml = wm * 64 + fm * 16 + ((lane >> 4) << 2) + rr;
                    out[(size_t)(m0 + ml) * Dd + col] = f2bf(acc[fm][fn][rr]);
                }
            }
    } else {
        short* out = yT + (size_t)s * H;
        const int b = m0 >> 9;
        const int il_base = (m0 & 511) + wm * 64 + ((lane >> 4) << 2);
        #pragma unroll
        for (int fm = 0; fm < 4; ++fm)
            #pragma unroll
            for (int fn = 0; fn < 4; ++fn) {
                const int n = (nt - 18) * 128 + wn * 64 + fn * 16 + (lane & 15);
                short4 pk;
                short* pks = reinterpret_cast<short*>(&pk);
                #pragma unroll
                for (int rr = 0; rr < 4; ++rr) pks[rr] = f2bf(acc[fm][fn][rr]);
                *reinterpret_cast<short4*>(
                    &out[((size_t)b * Dd + n) * Lr + il_base + fm * 16]) = pk;
            }
    }
}

// scores[s,b,i,j] = alpha*(gM_i . h_j + u_i + v_j + c + grel + rb[r]).
__global__ __launch_bounds__(256)
void scores2_k(const short* __restrict__ g,
               const short* __restrict__ h0, const short* __restrict__ h1,
               const float* __restrict__ rbv, float* __restrict__ scb)
{
    __shared__ short As[TILE], Bs[TILE];
    f32x4 acc[4][4] = {};
    const int sid = (blockIdx.x & 7) * 32 + (blockIdx.x >> 3);
    const int n0 = (sid & 3) * 128, m0 = ((sid >> 2) & 3) * 128;
    const int z = sid >> 4;
    const int s = z >> 3, b = z & 7;
    const short* gs = g + (size_t)s * GSZ;
    const short* A  = gs + (size_t)(b * Lr + m0) * 1280;
    const short* hB = (s ? h1 : h0) + (size_t)(b * Lr + n0) * Dd;
    gemm_core(A, 1280, hB, Dd, Dd, As, Bs, acc);

    float* out = scb + (size_t)s * SC;
    const float c = rbv[s * 132 + 129];
    const int lane = threadIdx.x & 63, w = threadIdx.x >> 6;
    const int wm = w >> 1, wn = w & 1;
    #pragma unroll
    for (int fm = 0; fm < 4; ++fm)
        #pragma unroll
        for (int fn = 0; fn < 4; ++fn) {
            const int j = n0 + wn * 64 + fn * 16 + (lane & 15);
            const float vj = bf2f(gs[(size_t)(b * Lr + j) * 1280 + 1154]);
            #pragma unroll
            for (int rr = 0; rr < 4; ++rr) {
                const int i = m0 + wm * 64 + fm * 16 + ((lane >> 4) << 2) + rr;
                const size_t grow = (size_t)(b * Lr + i) * 1280;
                const float ui = bf2f(gs[grow + 1153]);
                int d = j - i;
                d = d < -Mm ? -Mm : (d > Mm ? Mm : d);
                const int r = d + Mm;
                const float grel = bf2f(gs[grow + 1024 + r]);
                out[((size_t)b * Lr + i) * Lr + j] =
                    0.03125f * (acc[fm][fn][rr] + ui + vj + c + grel +
                                rbv[s * 132 + r]);
            }
        }
}

// Masked softmax both streams: grid (512, 8, 2)
__global__ __launch_bounds__(256)
void softmax2_k(const float* __restrict__ scb, const int* __restrict__ spw,
                float* __restrict__ out0, float* __restrict__ out1,
                short* __restrict__ probs, int t)
{
    const int i = blockIdx.x, b = blockIdx.y, s = blockIdx.z;
    const float* srow = scb + (size_t)s * SC + ((size_t)b * Lr + i) * Lr;
    const int tidx = threadIdx.x;
    float s0, s1;
    {
        int w = spw[b * Lr + tidx];
        s0 = (w != 0 && t <= w) ? srow[tidx] : -1e18f;
        w = spw[b * Lr + tidx + 256];
        s1 = (w != 0 && t <= w) ? srow[tidx + 256] : -1e18f;
    }
    float mx = fmaxf(s0, s1);
    #pragma unroll
    for (int off = 32; off > 0; off >>= 1) mx = fmaxf(mx, __shfl_down(mx, off));
    __shared__ float redm[4], reds[4];
    const int lane = tidx & 63, wid = tidx >> 6;
    if (lane == 0) redm[wid] = mx;
    __syncthreads();
    mx = fmaxf(fmaxf(redm[0], redm[1]), fmaxf(redm[2], redm[3]));
    const float e0 = expf(s0 - mx), e1 = expf(s1 - mx);
    float sum = e0 + e1;
    #pragma unroll
    for (int off = 32; off > 0; off >>= 1) sum += __shfl_down(sum, off);
    if (lane == 0) reds[wid] = sum;
    __syncthreads();
    const float inv = 1.f / (reds[0] + reds[1] + reds[2] + reds[3]);
    const float p0 = e0 * inv, p1 = e1 * inv;
    float* orow = (s ? out1 : out0) + (((size_t)b * Lr + i) * Tt + t) * Lr;
    orow[tidx]       = p0;
    orow[tidx + 256] = p1;
    short* prow = probs + (size_t)s * PS + ((size_t)b * Lr + i) * Lr;
    prow[tidx]       = f2bf(p0);
    prow[tidx + 256] = f2bf(p1);
}

// h' = relu(P@y + x + cb). grid 512, XCD-swizzled.
__global__ __launch_bounds__(256)
void pv2_k(const short* __restrict__ probs, const short* __restrict__ yT,
           const short* __restrict__ x, const float* __restrict__ cb,
           short* __restrict__ hn0, short* __restrict__ hn1)
{
    __shared__ short As[TILE], Bs[TILE];
    f32x4 acc[4][4] = {};
    const int sid = (blockIdx.x & 7) * 64 + (blockIdx.x >> 3);
    const int n0 = (sid & 7) * 128, m0 = ((sid >> 3) & 3) * 128;
    const int z = sid >> 5;
    const int s = z >> 3, b = z & 7;
    const short* A = probs + (size_t)s * PS + (size_t)(b * Lr + m0) * Lr;
    const short* B = yT + (size_t)s * H + (size_t)(b * Dd + n0) * Lr;
    gemm_core(A, Lr, B, Lr, Lr, As, Bs, acc);

    short* hout = s ? hn1 : hn0;
    const short* xs = x + (size_t)s * H;
    const int lane = threadIdx.x & 63, w = threadIdx.x >> 6;
    const int wm = w >> 1, wn = w & 1;
    #pragma unroll
    for (int fm = 0; fm < 4; ++fm)
        #pragma unroll
        for (int fn = 0; fn < 4; ++fn) {
            const int n = n0 + wn * 64 + fn * 16 + (lane & 15);
            const float bias = cb[n];
            #pragma unroll
            for (int rr = 0; rr < 4; ++rr) {
                const int row = b * Lr + m0 + wm * 64 + fm * 16 +
                                ((lane >> 4) << 2) + rr;
                const float v = fmaxf(acc[fm][fn][rr] +
                                      bf2f(xs[(size_t)row * Dd + n]) + bias, 0.f);
                hout[(size_t)row * Dd + n] = f2bf(v);
            }
        }
}

// W2 = Wk^T @ Wq -> W_aug rows 0-1023 (bf16). grid 128 = 2s x 8x8.
__global__ __launch_bounds__(256)
void w2_k(const short* __restrict__ wqT0, const short* __restrict__ wqT1,
          const short* __restrict__ wkT0, const short* __restrict__ wkT1,
          short* __restrict__ waug)
{
    __shared__ short As[TILE], Bs[TILE];
    f32x4 acc[4][4] = {};
    const int s = blockIdx.x >> 6, rem = blockIdx.x & 63;
    const int m0 = (rem >> 3) * 128, n0 = (rem & 7) * 128;
    const short* A = (s ? wkT1 : wkT0) + (size_t)m0 * Dd;
    const short* B = (s ? wqT1 : wqT0) + (size_t)n0 * Dd;
    gemm_core(A, Dd, B, Dd, Dd, As, Bs, acc);
    short* out = waug + (size_t)s * WASZ;
    const int lane = threadIdx.x & 63, w = threadIdx.x >> 6;
    const int wm = w >> 1, wn = w & 1;
    #pragma unroll
    for (int fm = 0; fm < 4; ++fm)
        #pragma unroll
        for (int fn = 0; fn < 4; ++fn) {
            const int nl = n0 + wn * 64 + fn * 16 + (lane & 15);
            #pragma unroll
            for (int rr = 0; rr < 4; ++rr) {
                const int ml = m0 + wm * 64 + fm * 16 + ((lane >> 4) << 2) + rr;
                out[(size_t)ml * Dd + nl] = f2bf(acc[fm][fn][rr]);
            }
        }
}

// RW = relp @ wqT^T -> W_aug rows 1024-1279 (rows >128 are zero via relp pad).
__global__ __launch_bounds__(256)
void rw2_k(const short* __restrict__ relp0, const short* __restrict__ relp1,
           const short* __restrict__ wqT0, const short* __restrict__ wqT1,
           short* __restrict__ waug)
{
    __shared__ short As[TILE], Bs[TILE];
    f32x4 acc[4][4] = {};
    const int s = blockIdx.x >> 4, rem = blockIdx.x & 15;
    const int m0 = (rem >> 3) * 128, n0 = (rem & 7) * 128;
    const short* A = (s ? relp1 : relp0) + (size_t)m0 * Dd;
    const short* B = (s ? wqT1 : wqT0) + (size_t)n0 * Dd;
    gemm_core(A, Dd, B, Dd, Dd, As, Bs, acc);
    short* out = waug + (size_t)s * WASZ + (size_t)1024 * Dd;
    const int lane = threadIdx.x & 63, w = threadIdx.x >> 6;
    const int wm = w >> 1, wn = w & 1;
    #pragma unroll
    for (int fm = 0; fm < 4; ++fm)
        #pragma unroll
        for (int fn = 0; fn < 4; ++fn) {
            const int nl = n0 + wn * 64 + fn * 16 + (lane & 15);
            #pragma unroll
            for (int rr = 0; rr < 4; ++rr) {
                const int ml = m0 + wm * 64 + fm * 16 + ((lane >> 4) << 2) + rr;
                out[(size_t)ml * Dd + nl] = f2bf(acc[fm][fn][rr]);
            }
        }
}

// rows 1153 (u = Wq^T bk) / 1154 (v = Wk^T bq). grid (1024, 2, 2), block 64.
__global__ __launch_bounds__(64)
void uv_k(const short* __restrict__ wqT0, const short* __restrict__ wqT1,
          const short* __restrict__ wkT0, const short* __restrict__ wkT1,
          const float* __restrict__ bq0, const float* __restrict__ bq1,
          const float* __restrict__ bk0, const float* __restrict__ bk1,
          short* __restrict__ waug)
{
    const int e = blockIdx.x, kind = blockIdx.y, s = blockIdx.z;
    const short* wT  = kind ? (s ? wkT1 : wkT0) : (s ? wqT1 : wqT0);
    const float* vec = kind ? (s ? bq1 : bq0) : (s ? bk1 : bk0);
    float sum = 0.f;
    for (int d = threadIdx.x; d < Dd; d += 64)
        sum += bf2f(wT[(size_t)e * Dd + d]) * vec[d];
    #pragma unroll
    for (int off = 32; off > 0; off >>= 1) sum += __shfl_down(sum, off);
    if (threadIdx.x == 0)
        waug[(size_t)s * WASZ + (size_t)(1153 + kind) * Dd + e] = f2bf(sum);
}

// rb[s][r] = rel_s[r,:].bq_s (r<129); slot 129 = bq.bk. grid (130,2), block 64.
__global__ __launch_bounds__(64)
void rb_k(const float* __restrict__ rel0, const float* __restrict__ rel1,
          const float* __restrict__ bq0, const float* __restrict__ bq1,
          const float* __restrict__ bk0, const float* __restrict__ bk1,
          float* __restrict__ rbv)
{
    const int r = blockIdx.x, s = blockIdx.y;
    const float* bq = s ? bq1 : bq0;
    float sum = 0.f;
    if (r < 129) {
        const float* rel = s ? rel1 : rel0;
        for (int n = threadIdx.x; n < Dd; n += 64)
            sum += rel[(size_t)r * Dd + n] * bq[n];
    } else {
        const float* bk = s ? bk1 : bk0;
        for (int n = threadIdx.x; n < Dd; n += 64)
            sum += bq[n] * bk[n];
    }
    #pragma unroll
    for (int off = 32; off > 0; off >>= 1) sum += __shfl_down(sum, off);
    if (threadIdx.x == 0) rbv[s * 132 + r] = sum;
}

// dst[e][n] = f2bf(src[n][e])  64x64 LDS tiles, grid (16,16)
__global__ __launch_bounds__(256)
void transpose_f2bf_k(const float* __restrict__ src, short* __restrict__ dst)
{
    __shared__ float tile[64][65];
    const int r0 = blockIdx.y * 64, c0 = blockIdx.x * 64;
    const int col = threadIdx.x & 63, row4 = threadIdx.x >> 6;
    #pragma unroll
    for (int rr = 0; rr < 16; ++rr)
        tile[row4 + rr * 4][col] = src[(size_t)(r0 + row4 + rr * 4) * Dd + c0 + col];
    __syncthreads();
    #pragma unroll
    for (int rr = 0; rr < 16; ++rr)
        dst[(size_t)(c0 + row4 + rr * 4) * Dd + r0 + col] =
            f2bf(tile[col][row4 + rr * 4]);
}

__global__ void masks_k(const int* __restrict__ spw, float* __restrict__ out2)
{
    const int idx = blockIdx.x * 256 + threadIdx.x;
    if (idx < BL) {
        const int w = spw[idx];
        #pragma unroll
        for (int t = 0; t < Tt; ++t)
            out2[(size_t)idx * Tt + t] = (w != 0 && t <= w) ? 1.f : 0.f;
    }
}

__global__ void f2bf_k(const float* __restrict__ src, short* __restrict__ dst, int n)
{
    const int idx = blockIdx.x * 256 + threadIdx.x;
    if (idx < n) dst[idx] = f2bf(src[idx]);
}

__global__ void relpad_k(const float* __restrict__ rel, short* __restrict__ dst)
{
    const int idx = blockIdx.x * 256 + threadIdx.x;   // 256*1024 total
    if (idx < 256 * 1024) {
        const int row = idx >> 10;
        dst[idx] = (row < 129) ? f2bf(rel[idx]) : (short)0;
    }
}

__global__ void hidinit_k(const float* __restrict__ hid,
                          short* __restrict__ h_st, short* __restrict__ h_ed)
{
    const int idx = blockIdx.x * 256 + threadIdx.x;
    if (idx < BL * Dd) {
        const short s = f2bf(hid[idx]);
        h_st[idx] = s;
        h_ed[idx] = s;
    }
}

} // namespace

extern "C" void kernel_launch(void* const* d_in, const int* in_sizes, int n_in,
                              void* d_out, int out_size, void* d_ws, size_t ws_size,
                              hipStream_t stream)
{
    const float* hid  = (const float*)d_in[0];
    const int*   spw  = (const int*)d_in[1];
    const float* Wq[2] = {(const float*)d_in[2], (const float*)d_in[7]};
    const float* bq[2] = {(const float*)d_in[3], (const float*)d_in[8]};
    const float* Wk[2] = {(const float*)d_in[4], (const float*)d_in[9]};
    const float* bk[2] = {(const float*)d_in[5], (const float*)d_in[10]};
    const float* rel[2]= {(const float*)d_in[6], (const float*)d_in[11]};
    const float* combW = (const float*)d_in[12];
    const float* combB = (const float*)d_in[13];

    float* out0 = (float*)d_out;
    float* out1 = out0 + (size_t)BL * Tt * Lr;
    float* out2 = out1 + (size_t)BL * Tt * Lr;

    // ---- workspace layout ----
    short* wsS = (short*)d_ws;
    size_t cur = 0;
    short* hbuf[2][2];
    hbuf[0][0] = wsS + cur; cur += H;
    hbuf[0][1] = wsS + cur; cur += H;
    hbuf[1][0] = wsS + cur; cur += H;
    hbuf[1][1] = wsS + cur; cur += H;
    short* g   = wsS + cur; cur += 2 * GSZ;
    short* x   = wsS + cur; cur += 2 * H;
    short* yT  = wsS + cur; cur += 2 * H;
    short* probs = wsS + cur; cur += 2 * PS;
    short* waug  = wsS + cur; cur += 2 * WASZ;
    short* combWb = wsS + cur; cur += (size_t)Dd * 2 * Dd;
    short* relp[2];
    relp[0] = wsS + cur; cur += (size_t)256 * Dd;
    relp[1] = wsS + cur; cur += (size_t)256 * Dd;
    float* wsF = (float*)(wsS + cur);
    float* rbv = wsF;                            // 2*132 (slot 129 = c)
    float* scb = wsF + 2 * 132;                  // 2 * SC fp32
    // setup-only transposed weights alias scb (scb written first at step 0)
    short* wqT[2] = {(short*)scb, (short*)scb + (size_t)Dd * Dd};
    short* wkT[2] = {(short*)scb + 2 * (size_t)Dd * Dd,
                     (short*)scb + 3 * (size_t)Dd * Dd};

    // ---- setup ----
    const int DD = Dd * Dd;
    f2bf_k<<<dim3((2 * DD + 255) / 256), 256, 0, stream>>>(combW, combWb, 2 * DD);
    relpad_k<<<dim3(256 * Dd / 256), 256, 0, stream>>>(rel[0], relp[0]);
    relpad_k<<<dim3(256 * Dd / 256), 256, 0, stream>>>(rel[1], relp[1]);
    transpose_f2bf_k<<<dim3(16, 16), 256, 0, stream>>>(Wq[0], wqT[0]);
    transpose_f2bf_k<<<dim3(16, 16), 256, 0, stream>>>(Wq[1], wqT[1]);
    transpose_f2bf_k<<<dim3(16, 16), 256, 0, stream>>>(Wk[0], wkT[0]);
    transpose_f2bf_k<<<dim3(16, 16), 256, 0, stream>>>(Wk[1], wkT[1]);
    w2_k<<<dim3(128), 256, 0, stream>>>(wqT[0], wqT[1], wkT[0], wkT[1], waug);
    rw2_k<<<dim3(32), 256, 0, stream>>>(relp[0], relp[1], wqT[0], wqT[1], waug);
    uv_k<<<dim3(1024, 2, 2), 64, 0, stream>>>(wqT[0], wqT[1], wkT[0], wkT[1],
                                              bq[0], bq[1], bk[0], bk[1], waug);
    rb_k<<<dim3(130, 2), 64, 0, stream>>>(rel[0], rel[1], bq[0], bq[1],
                                          bk[0], bk[1], rbv);
    hidinit_k<<<dim3((int)(H / 256)), 256, 0, stream>>>(hid, hbuf[0][0], hbuf[1][0]);
    masks_k<<<dim3((BL + 255) / 256), 256, 0, stream>>>(spw, out2);

    int curb = 0;
    for (int t = 0; t < Tt; ++t) {
        short* h0 = hbuf[0][curb], *h1 = hbuf[1][curb];
        short* hn0 = hbuf[0][curb ^ 1], *hn1 = hbuf[1][curb ^ 1];
        gg_k<<<dim3(1664), 256, 0, stream>>>(h0, h1, waug, combWb, g, x, yT);
        scores2_k<<<dim3(256), 256, 0, stream>>>(g, h0, h1, rbv, scb);
        softmax2_k<<<dim3(Lr, Bb, 2), 256, 0, stream>>>(scb, spw, out0, out1, probs, t);
        pv2_k<<<dim3(512), 256, 0, stream>>>(probs, yT, x, combB, hn0, hn1);
        curb ^= 1;
    }
}

// Round 11
// 1225.749 us; speedup vs baseline: 1.4191x; 1.2278x over previous
//
#include <hip/hip_runtime.h>
#include <hip/hip_bf16.h>

namespace {

constexpr int Bb = 8;
constexpr int Lr = 512;
constexpr int Dd = 1024;
constexpr int Mm = 64;
constexpr int Tt = 8;
constexpr int BL = Bb * Lr;      // 4096

constexpr size_t H    = (size_t)BL * Dd;        // per-stream hid elems (4096x1024)
constexpr size_t SC   = (size_t)Bb * Lr * Lr;   // per-stream scores elems
constexpr size_t PS   = SC;                     // per-stream probs elems
constexpr size_t GSZ  = (size_t)BL * 1280;      // per-stream g elems
constexpr size_t WASZ = (size_t)1280 * Dd;      // per-stream W_aug elems

constexpr int TILE = 128 * 64;                  // one LDS tile (shorts), 128^2 core

typedef __attribute__((ext_vector_type(8))) short bf16x8;
typedef __attribute__((ext_vector_type(4))) float f32x4;

__device__ __forceinline__ short f2bf(float x) {
    __hip_bfloat16 h = __float2bfloat16(x);
    return *reinterpret_cast<short*>(&h);
}
__device__ __forceinline__ float bf2f(short s) {
    unsigned int u = ((unsigned int)(unsigned short)s) << 16;
    return __uint_as_float(u);
}

// ---------------------------------------------------------------------------
// 128^2 core (m97 structure) — used by scores/pv/w2/rw2.
// ---------------------------------------------------------------------------
__device__ __forceinline__ void gemm_core(
    const short* __restrict__ A, int lda,
    const short* __restrict__ Bm, int ldb, int K,
    short* As, short* Bs, f32x4 acc[4][4])
{
    const int tid  = threadIdx.x;
    const int lane = tid & 63;
    const int w    = tid >> 6;
    const int wm   = w >> 1, wn = w & 1;
    const int lr   = lane >> 3;         // row within 8-row group
    const int lc   = (lane & 7) << 3;   // elem col: 0,8,..,56

    for (int k0 = 0; k0 < K; k0 += 64) {
        #pragma unroll
        for (int i = 0; i < 4; ++i) {
            const int r0 = (i * 4 + w) * 8;
            const short* gA = A + (size_t)(r0 + lr) * lda + k0 + lc;
            __builtin_amdgcn_global_load_lds(
                (const __attribute__((address_space(1))) void*)gA,
                (__attribute__((address_space(3))) void*)(As + r0 * 64), 16, 0, 0);
            const short* gB = Bm + (size_t)(r0 + lr) * ldb + k0 + lc;
            __builtin_amdgcn_global_load_lds(
                (const __attribute__((address_space(1))) void*)gB,
                (__attribute__((address_space(3))) void*)(Bs + r0 * 64), 16, 0, 0);
        }
        __syncthreads();
        #pragma unroll
        for (int ks = 0; ks < 2; ++ks) {
            bf16x8 af[4], bb[4];
            #pragma unroll
            for (int f = 0; f < 4; ++f) {
                af[f] = *(const bf16x8*)(As + (wm * 64 + f * 16 + (lane & 15)) * 64
                                            + ks * 32 + ((lane >> 4) << 3));
                bb[f] = *(const bf16x8*)(Bs + (wn * 64 + f * 16 + (lane & 15)) * 64
                                            + ks * 32 + ((lane >> 4) << 3));
            }
            #pragma unroll
            for (int fm = 0; fm < 4; ++fm)
                #pragma unroll
                for (int fn = 0; fn < 4; ++fn)
                    acc[fm][fn] = __builtin_amdgcn_mfma_f32_16x16x32_bf16(
                        af[fm], bb[fn], acc[fm][fn], 0, 0, 0);
        }
        __syncthreads();
    }
}

// ---------------------------------------------------------------------------
// 8-phase 256^2 G-GEMM (T2 swizzle + T3/T4 counted vmcnt + T5 setprio).
// [g | x | yT] = h @ Wtot^T, both streams. Grid 416 = 8 xcd * (13 nt * 4 mt),
// 512 threads (8 waves 2M x 4N), LDS 128 KB dbuf. K=1024 = 16 tiles of 64.
// Per K-tile: 4 quadrant-phases; stages for tile t+1 spread across phases
// in order B0,B1 | B2,B3 | A0,A1 | A2,A3 (A-unit q = quadrant-q rows).
// Per-phase: vmcnt(own) -> s_barrier -> sched_barrier -> reads/stages/MFMA.
// ---------------------------------------------------------------------------
template<int Q>
__device__ __forceinline__ void gg_phase_mfma(
    const short* __restrict__ Ab, f32x4 (&acc)[8][4], const bf16x8 (&bq)[4][2],
    int wm, int lane, int hi3, int sw)
{
    bf16x8 a[2][2];
    #pragma unroll
    for (int e = 0; e < 2; ++e)
        #pragma unroll
        for (int ks = 0; ks < 2; ++ks)
            a[e][ks] = *(const bf16x8*)(Ab + (Q * 64 + wm * 32 + e * 16 + (lane & 15)) * 64
                                           + ((ks * 32 + hi3) ^ sw));
    __builtin_amdgcn_s_setprio(1);
    #pragma unroll
    for (int fn = 0; fn < 4; ++fn)
        #pragma unroll
        for (int e = 0; e < 2; ++e)
            #pragma unroll
            for (int ks = 0; ks < 2; ++ks)
                acc[2 * Q + e][fn] = __builtin_amdgcn_mfma_f32_16x16x32_bf16(
                    a[e][ks], bq[fn][ks], acc[2 * Q + e][fn], 0, 0, 0);
    __builtin_amdgcn_s_setprio(0);
}

__global__ __launch_bounds__(512, 2)
void gg_k(const short* __restrict__ h0, const short* __restrict__ h1,
          const short* __restrict__ waug, const short* __restrict__ wc,
          short* __restrict__ g, short* __restrict__ x, short* __restrict__ yT)
{
    __shared__ short lds[65536];          // [2 dbuf][A 16384 | B 16384]
    f32x4 acc[8][4] = {};
    bf16x8 bq[4][2];
    const int tid  = threadIdx.x;
    const int lane = tid & 63;
    const int w    = tid >> 6;
    const int wm   = w >> 2, wn = w & 3;

    const int xcd = blockIdx.x & 7;
    const int l   = blockIdx.x >> 3;      // 0..51
    const int nt  = l >> 2;               // 0..12
    const int mt  = xcd * 4 + (l & 3);    // 0..31
    const int s   = mt >> 4;
    const int m0  = (mt & 15) * 256;
    const short* h = s ? h1 : h0;
    const short* Bg; int ldb;
    if (nt < 5)      { Bg = waug + (size_t)s * WASZ + (size_t)nt * 256 * Dd; ldb = Dd; }
    else if (nt < 9) { Bg = wc + (size_t)(nt - 5) * 256 * 2048;              ldb = 2048; }
    else             { Bg = wc + 1024 + (size_t)(nt - 9) * 256 * 2048;       ldb = 2048; }
    const short* Ag = h + (size_t)m0 * Dd;

    const int lr      = tid >> 3;                      // 0..63
    const int gcol    = ((tid & 7) * 8) ^ ((lr & 7) << 3);   // swizzled src col (elems)
    const int arowoff = lr + (lr < 32 ? 0 : 96);       // A-unit row offset

    auto stA = [&](int kt, int pb, int q) {
        const short* src = Ag + (size_t)(q * 32 + arowoff) * Dd + kt * 64 + gcol;
        short* dst = lds + pb * 32768 + q * 4096 + tid * 8;
        __builtin_amdgcn_global_load_lds(
            (const __attribute__((address_space(1))) void*)src,
            (__attribute__((address_space(3))) void*)dst, 16, 0, 0);
    };
    auto stB = [&](int kt, int pb, int u) {
        const short* src = Bg + (size_t)(u * 64 + lr) * ldb + kt * 64 + gcol;
        short* dst = lds + pb * 32768 + 16384 + u * 4096 + tid * 8;
        __builtin_amdgcn_global_load_lds(
            (const __attribute__((address_space(1))) void*)src,
            (__attribute__((address_space(3))) void*)dst, 16, 0, 0);
    };

    // prologue: tile 0 -> buf 0 (FIFO order must match steady-state issues)
    stB(0, 0, 0); stB(0, 0, 1); stB(0, 0, 2); stB(0, 0, 3);
    stA(0, 0, 0); stA(0, 0, 1); stA(0, 0, 2); stA(0, 0, 3);

    const int hi3 = (lane >> 4) << 3;
    const int sw  = (lane & 7) << 3;

    int p = 0;
    for (int kt = 0; kt < 16; ++kt, p ^= 1) {
        const short* Ab = lds + p * 32768;
        const short* Bb = lds + p * 32768 + 16384;
        const int ktn = kt + 1;
        const bool nl = (ktn < 16);
        // ---- phase 0 (quadrant 0; needs B0..B3 + A0 of this tile) ----
        asm volatile("s_waitcnt vmcnt(3)" ::: "memory");
        __builtin_amdgcn_s_barrier();
        __builtin_amdgcn_sched_barrier(0);
        if (nl) { stB(ktn, p ^ 1, 0); stB(ktn, p ^ 1, 1); }
        #pragma unroll
        for (int fn = 0; fn < 4; ++fn) {
            bq[fn][0] = *(const bf16x8*)(Bb + (wn * 64 + fn * 16 + (lane & 15)) * 64
                                            + ((0 + hi3) ^ sw));
            bq[fn][1] = *(const bf16x8*)(Bb + (wn * 64 + fn * 16 + (lane & 15)) * 64
                                            + ((32 + hi3) ^ sw));
        }
        gg_phase_mfma<0>(Ab, acc, bq, wm, lane, hi3, sw);
        // ---- phase 1 (quadrant 1; needs A1) ----
        if (nl) asm volatile("s_waitcnt vmcnt(4)" ::: "memory");
        else    asm volatile("s_waitcnt vmcnt(2)" ::: "memory");
        __builtin_amdgcn_s_barrier();
        __builtin_amdgcn_sched_barrier(0);
        if (nl) { stB(ktn, p ^ 1, 2); stB(ktn, p ^ 1, 3); }
        gg_phase_mfma<1>(Ab, acc, bq, wm, lane, hi3, sw);
        // ---- phase 2 (quadrant 2; needs A2) ----
        if (nl) asm volatile("s_waitcnt vmcnt(5)" ::: "memory");
        else    asm volatile("s_waitcnt vmcnt(1)" ::: "memory");
        __builtin_amdgcn_s_barrier();
        __builtin_amdgcn_sched_barrier(0);
        if (nl) { stA(ktn, p ^ 1, 0); stA(ktn, p ^ 1, 1); }
        gg_phase_mfma<2>(Ab, acc, bq, wm, lane, hi3, sw);
        // ---- phase 3 (quadrant 3; needs A3) ----
        if (nl) asm volatile("s_waitcnt vmcnt(6)" ::: "memory");
        else    asm volatile("s_waitcnt vmcnt(0)" ::: "memory");
        __builtin_amdgcn_s_barrier();
        __builtin_amdgcn_sched_barrier(0);
        if (nl) { stA(ktn, p ^ 1, 2); stA(ktn, p ^ 1, 3); }
        gg_phase_mfma<3>(Ab, acc, bq, wm, lane, hi3, sw);
    }

    // ---- epilogue ----
    const int r4 = (lane >> 4) << 2;
    const int cb = wn * 64 + (lane & 15);
    if (nt < 5) {
        short* out = g + (size_t)s * GSZ;
        #pragma unroll
        for (int fm = 0; fm < 8; ++fm)
            #pragma unroll
            for (int fn = 0; fn < 4; ++fn) {
                const int col = nt * 256 + cb + fn * 16;
                #pragma unroll
                for (int rr = 0; rr < 4; ++rr) {
                    const int row = m0 + wm * 128 + fm * 16 + r4 + rr;
                    out[(size_t)row * 1280 + col] = f2bf(acc[fm][fn][rr]);
                }
            }
    } else if (nt < 9) {
        short* out = x + (size_t)s * H;
        #pragma unroll
        for (int fm = 0; fm < 8; ++fm)
            #pragma unroll
            for (int fn = 0; fn < 4; ++fn) {
                const int col = (nt - 5) * 256 + cb + fn * 16;
                #pragma unroll
                for (int rr = 0; rr < 4; ++rr) {
                    const int row = m0 + wm * 128 + fm * 16 + r4 + rr;
                    out[(size_t)row * Dd + col] = f2bf(acc[fm][fn][rr]);
                }
            }
    } else {
        short* out = yT + (size_t)s * H;
        const int b = m0 >> 9;
        const int il0 = (m0 & 511) + wm * 128 + r4;
        #pragma unroll
        for (int fm = 0; fm < 8; ++fm)
            #pragma unroll
            for (int fn = 0; fn < 4; ++fn) {
                const int n = (nt - 9) * 256 + cb + fn * 16;
                short4 pk;
                short* pks = reinterpret_cast<short*>(&pk);
                #pragma unroll
                for (int rr = 0; rr < 4; ++rr) pks[rr] = f2bf(acc[fm][fn][rr]);
                *reinterpret_cast<short4*>(
                    &out[((size_t)b * Dd + n) * Lr + il0 + fm * 16]) = pk;
            }
    }
}

// scores[s,b,i,j] = alpha*(gM_i . h_j + u_i + v_j + c + grel + rb[r]).
__global__ __launch_bounds__(256)
void scores2_k(const short* __restrict__ g,
               const short* __restrict__ h0, const short* __restrict__ h1,
               const float* __restrict__ rbv, float* __restrict__ scb)
{
    __shared__ short As[TILE], Bs[TILE];
    f32x4 acc[4][4] = {};
    const int sid = (blockIdx.x & 7) * 32 + (blockIdx.x >> 3);
    const int n0 = (sid & 3) * 128, m0 = ((sid >> 2) & 3) * 128;
    const int z = sid >> 4;
    const int s = z >> 3, b = z & 7;
    const short* gs = g + (size_t)s * GSZ;
    const short* A  = gs + (size_t)(b * Lr + m0) * 1280;
    const short* hB = (s ? h1 : h0) + (size_t)(b * Lr + n0) * Dd;
    gemm_core(A, 1280, hB, Dd, Dd, As, Bs, acc);

    float* out = scb + (size_t)s * SC;
    const float c = rbv[s * 132 + 129];
    const int lane = threadIdx.x & 63, w = threadIdx.x >> 6;
    const int wm = w >> 1, wn = w & 1;
    #pragma unroll
    for (int fm = 0; fm < 4; ++fm)
        #pragma unroll
        for (int fn = 0; fn < 4; ++fn) {
            const int j = n0 + wn * 64 + fn * 16 + (lane & 15);
            const float vj = bf2f(gs[(size_t)(b * Lr + j) * 1280 + 1154]);
            #pragma unroll
            for (int rr = 0; rr < 4; ++rr) {
                const int i = m0 + wm * 64 + fm * 16 + ((lane >> 4) << 2) + rr;
                const size_t grow = (size_t)(b * Lr + i) * 1280;
                const float ui = bf2f(gs[grow + 1153]);
                int d = j - i;
                d = d < -Mm ? -Mm : (d > Mm ? Mm : d);
                const int r = d + Mm;
                const float grel = bf2f(gs[grow + 1024 + r]);
                out[((size_t)b * Lr + i) * Lr + j] =
                    0.03125f * (acc[fm][fn][rr] + ui + vj + c + grel +
                                rbv[s * 132 + r]);
            }
        }
}

// Masked softmax both streams: grid (512, 8, 2)
__global__ __launch_bounds__(256)
void softmax2_k(const float* __restrict__ scb, const int* __restrict__ spw,
                float* __restrict__ out0, float* __restrict__ out1,
                short* __restrict__ probs, int t)
{
    const int i = blockIdx.x, b = blockIdx.y, s = blockIdx.z;
    const float* srow = scb + (size_t)s * SC + ((size_t)b * Lr + i) * Lr;
    const int tidx = threadIdx.x;
    float s0, s1;
    {
        int w = spw[b * Lr + tidx];
        s0 = (w != 0 && t <= w) ? srow[tidx] : -1e18f;
        w = spw[b * Lr + tidx + 256];
        s1 = (w != 0 && t <= w) ? srow[tidx + 256] : -1e18f;
    }
    float mx = fmaxf(s0, s1);
    #pragma unroll
    for (int off = 32; off > 0; off >>= 1) mx = fmaxf(mx, __shfl_down(mx, off));
    __shared__ float redm[4], reds[4];
    const int lane = tidx & 63, wid = tidx >> 6;
    if (lane == 0) redm[wid] = mx;
    __syncthreads();
    mx = fmaxf(fmaxf(redm[0], redm[1]), fmaxf(redm[2], redm[3]));
    const float e0 = expf(s0 - mx), e1 = expf(s1 - mx);
    float sum = e0 + e1;
    #pragma unroll
    for (int off = 32; off > 0; off >>= 1) sum += __shfl_down(sum, off);
    if (lane == 0) reds[wid] = sum;
    __syncthreads();
    const float inv = 1.f / (reds[0] + reds[1] + reds[2] + reds[3]);
    const float p0 = e0 * inv, p1 = e1 * inv;
    float* orow = (s ? out1 : out0) + (((size_t)b * Lr + i) * Tt + t) * Lr;
    orow[tidx]       = p0;
    orow[tidx + 256] = p1;
    short* prow = probs + (size_t)s * PS + ((size_t)b * Lr + i) * Lr;
    prow[tidx]       = f2bf(p0);
    prow[tidx + 256] = f2bf(p1);
}

// h' = relu(P@y + x + cb). grid 512, XCD-swizzled.
__global__ __launch_bounds__(256)
void pv2_k(const short* __restrict__ probs, const short* __restrict__ yT,
           const short* __restrict__ x, const float* __restrict__ cb,
           short* __restrict__ hn0, short* __restrict__ hn1)
{
    __shared__ short As[TILE], Bs[TILE];
    f32x4 acc[4][4] = {};
    const int sid = (blockIdx.x & 7) * 64 + (blockIdx.x >> 3);
    const int n0 = (sid & 7) * 128, m0 = ((sid >> 3) & 3) * 128;
    const int z = sid >> 5;
    const int s = z >> 3, b = z & 7;
    const short* A = probs + (size_t)s * PS + (size_t)(b * Lr + m0) * Lr;
    const short* B = yT + (size_t)s * H + (size_t)(b * Dd + n0) * Lr;
    gemm_core(A, Lr, B, Lr, Lr, As, Bs, acc);

    short* hout = s ? hn1 : hn0;
    const short* xs = x + (size_t)s * H;
    const int lane = threadIdx.x & 63, w = threadIdx.x >> 6;
    const int wm = w >> 1, wn = w & 1;
    #pragma unroll
    for (int fm = 0; fm < 4; ++fm)
        #pragma unroll
        for (int fn = 0; fn < 4; ++fn) {
            const int n = n0 + wn * 64 + fn * 16 + (lane & 15);
            const float bias = cb[n];
            #pragma unroll
            for (int rr = 0; rr < 4; ++rr) {
                const int row = b * Lr + m0 + wm * 64 + fm * 16 +
                                ((lane >> 4) << 2) + rr;
                const float v = fmaxf(acc[fm][fn][rr] +
                                      bf2f(xs[(size_t)row * Dd + n]) + bias, 0.f);
                hout[(size_t)row * Dd + n] = f2bf(v);
            }
        }
}

// W2 = Wk^T @ Wq -> W_aug rows 0-1023 (bf16). grid 128 = 2s x 8x8.
__global__ __launch_bounds__(256)
void w2_k(const short* __restrict__ wqT0, const short* __restrict__ wqT1,
          const short* __restrict__ wkT0, const short* __restrict__ wkT1,
          short* __restrict__ waug)
{
    __shared__ short As[TILE], Bs[TILE];
    f32x4 acc[4][4] = {};
    const int s = blockIdx.x >> 6, rem = blockIdx.x & 63;
    const int m0 = (rem >> 3) * 128, n0 = (rem & 7) * 128;
    const short* A = (s ? wkT1 : wkT0) + (size_t)m0 * Dd;
    const short* B = (s ? wqT1 : wqT0) + (size_t)n0 * Dd;
    gemm_core(A, Dd, B, Dd, Dd, As, Bs, acc);
    short* out = waug + (size_t)s * WASZ;
    const int lane = threadIdx.x & 63, w = threadIdx.x >> 6;
    const int wm = w >> 1, wn = w & 1;
    #pragma unroll
    for (int fm = 0; fm < 4; ++fm)
        #pragma unroll
        for (int fn = 0; fn < 4; ++fn) {
            const int nl = n0 + wn * 64 + fn * 16 + (lane & 15);
            #pragma unroll
            for (int rr = 0; rr < 4; ++rr) {
                const int ml = m0 + wm * 64 + fm * 16 + ((lane >> 4) << 2) + rr;
                out[(size_t)ml * Dd + nl] = f2bf(acc[fm][fn][rr]);
            }
        }
}

// RW = relp @ wqT^T -> W_aug rows 1024-1279 (rows >128 zero via relp pad).
__global__ __launch_bounds__(256)
void rw2_k(const short* __restrict__ relp0, const short* __restrict__ relp1,
           const short* __restrict__ wqT0, const short* __restrict__ wqT1,
           short* __restrict__ waug)
{
    __shared__ short As[TILE], Bs[TILE];
    f32x4 acc[4][4] = {};
    const int s = blockIdx.x >> 4, rem = blockIdx.x & 15;
    const int m0 = (rem >> 3) * 128, n0 = (rem & 7) * 128;
    const short* A = (s ? relp1 : relp0) + (size_t)m0 * Dd;
    const short* B = (s ? wqT1 : wqT0) + (size_t)n0 * Dd;
    gemm_core(A, Dd, B, Dd, Dd, As, Bs, acc);
    short* out = waug + (size_t)s * WASZ + (size_t)1024 * Dd;
    const int lane = threadIdx.x & 63, w = threadIdx.x >> 6;
    const int wm = w >> 1, wn = w & 1;
    #pragma unroll
    for (int fm = 0; fm < 4; ++fm)
        #pragma unroll
        for (int fn = 0; fn < 4; ++fn) {
            const int nl = n0 + wn * 64 + fn * 16 + (lane & 15);
            #pragma unroll
            for (int rr = 0; rr < 4; ++rr) {
                const int ml = m0 + wm * 64 + fm * 16 + ((lane >> 4) << 2) + rr;
                out[(size_t)ml * Dd + nl] = f2bf(acc[fm][fn][rr]);
            }
        }
}

// rows 1153 (u = Wq^T bk) / 1154 (v = Wk^T bq). grid (1024, 2, 2), block 64.
__global__ __launch_bounds__(64)
void uv_k(const short* __restrict__ wqT0, const short* __restrict__ wqT1,
          const short* __restrict__ wkT0, const short* __restrict__ wkT1,
          const float* __restrict__ bq0, const float* __restrict__ bq1,
          const float* __restrict__ bk0, const float* __restrict__ bk1,
          short* __restrict__ waug)
{
    const int e = blockIdx.x, kind = blockIdx.y, s = blockIdx.z;
    const short* wT  = kind ? (s ? wkT1 : wkT0) : (s ? wqT1 : wqT0);
    const float* vec = kind ? (s ? bq1 : bq0) : (s ? bk1 : bk0);
    float sum = 0.f;
    for (int d = threadIdx.x; d < Dd; d += 64)
        sum += bf2f(wT[(size_t)e * Dd + d]) * vec[d];
    #pragma unroll
    for (int off = 32; off > 0; off >>= 1) sum += __shfl_down(sum, off);
    if (threadIdx.x == 0)
        waug[(size_t)s * WASZ + (size_t)(1153 + kind) * Dd + e] = f2bf(sum);
}

// rb[s][r] = rel_s[r,:].bq_s (r<129); slot 129 = bq.bk. grid (130,2), block 64.
__global__ __launch_bounds__(64)
void rb_k(const float* __restrict__ rel0, const float* __restrict__ rel1,
          const float* __restrict__ bq0, const float* __restrict__ bq1,
          const float* __restrict__ bk0, const float* __restrict__ bk1,
          float* __restrict__ rbv)
{
    const int r = blockIdx.x, s = blockIdx.y;
    const float* bq = s ? bq1 : bq0;
    float sum = 0.f;
    if (r < 129) {
        const float* rel = s ? rel1 : rel0;
        for (int n = threadIdx.x; n < Dd; n += 64)
            sum += rel[(size_t)r * Dd + n] * bq[n];
    } else {
        const float* bk = s ? bk1 : bk0;
        for (int n = threadIdx.x; n < Dd; n += 64)
            sum += bq[n] * bk[n];
    }
    #pragma unroll
    for (int off = 32; off > 0; off >>= 1) sum += __shfl_down(sum, off);
    if (threadIdx.x == 0) rbv[s * 132 + r] = sum;
}

// dst[e][n] = f2bf(src[n][e])  64x64 LDS tiles, grid (16,16)
__global__ __launch_bounds__(256)
void transpose_f2bf_k(const float* __restrict__ src, short* __restrict__ dst)
{
    __shared__ float tile[64][65];
    const int r0 = blockIdx.y * 64, c0 = blockIdx.x * 64;
    const int col = threadIdx.x & 63, row4 = threadIdx.x >> 6;
    #pragma unroll
    for (int rr = 0; rr < 16; ++rr)
        tile[row4 + rr * 4][col] = src[(size_t)(r0 + row4 + rr * 4) * Dd + c0 + col];
    __syncthreads();
    #pragma unroll
    for (int rr = 0; rr < 16; ++rr)
        dst[(size_t)(c0 + row4 + rr * 4) * Dd + r0 + col] =
            f2bf(tile[col][row4 + rr * 4]);
}

__global__ void masks_k(const int* __restrict__ spw, float* __restrict__ out2)
{
    const int idx = blockIdx.x * 256 + threadIdx.x;
    if (idx < BL) {
        const int w = spw[idx];
        #pragma unroll
        for (int t = 0; t < Tt; ++t)
            out2[(size_t)idx * Tt + t] = (w != 0 && t <= w) ? 1.f : 0.f;
    }
}

__global__ void f2bf_k(const float* __restrict__ src, short* __restrict__ dst, int n)
{
    const int idx = blockIdx.x * 256 + threadIdx.x;
    if (idx < n) dst[idx] = f2bf(src[idx]);
}

__global__ void relpad_k(const float* __restrict__ rel, short* __restrict__ dst)
{
    const int idx = blockIdx.x * 256 + threadIdx.x;   // 256*1024 total
    if (idx < 256 * 1024) {
        const int row = idx >> 10;
        dst[idx] = (row < 129) ? f2bf(rel[idx]) : (short)0;
    }
}

__global__ void hidinit_k(const float* __restrict__ hid,
                          short* __restrict__ h_st, short* __restrict__ h_ed)
{
    const int idx = blockIdx.x * 256 + threadIdx.x;
    if (idx < BL * Dd) {
        const short s = f2bf(hid[idx]);
        h_st[idx] = s;
        h_ed[idx] = s;
    }
}

} // namespace

extern "C" void kernel_launch(void* const* d_in, const int* in_sizes, int n_in,
                              void* d_out, int out_size, void* d_ws, size_t ws_size,
                              hipStream_t stream)
{
    const float* hid  = (const float*)d_in[0];
    const int*   spw  = (const int*)d_in[1];
    const float* Wq[2] = {(const float*)d_in[2], (const float*)d_in[7]};
    const float* bq[2] = {(const float*)d_in[3], (const float*)d_in[8]};
    const float* Wk[2] = {(const float*)d_in[4], (const float*)d_in[9]};
    const float* bk[2] = {(const float*)d_in[5], (const float*)d_in[10]};
    const float* rel[2]= {(const float*)d_in[6], (const float*)d_in[11]};
    const float* combW = (const float*)d_in[12];
    const float* combB = (const float*)d_in[13];

    float* out0 = (float*)d_out;
    float* out1 = out0 + (size_t)BL * Tt * Lr;
    float* out2 = out1 + (size_t)BL * Tt * Lr;

    // ---- workspace layout ----
    short* wsS = (short*)d_ws;
    size_t cur = 0;
    short* hbuf[2][2];
    hbuf[0][0] = wsS + cur; cur += H;
    hbuf[0][1] = wsS + cur; cur += H;
    hbuf[1][0] = wsS + cur; cur += H;
    hbuf[1][1] = wsS + cur; cur += H;
    short* g   = wsS + cur; cur += 2 * GSZ;
    short* x   = wsS + cur; cur += 2 * H;
    short* yT  = wsS + cur; cur += 2 * H;
    short* probs = wsS + cur; cur += 2 * PS;
    short* waug  = wsS + cur; cur += 2 * WASZ;
    short* combWb = wsS + cur; cur += (size_t)Dd * 2 * Dd;
    short* relp[2];
    relp[0] = wsS + cur; cur += (size_t)256 * Dd;
    relp[1] = wsS + cur; cur += (size_t)256 * Dd;
    float* wsF = (float*)(wsS + cur);
    float* rbv = wsF;                            // 2*132 (slot 129 = c)
    float* scb = wsF + 2 * 132;                  // 2 * SC fp32
    // setup-only transposed weights alias scb (scb written first at step 0)
    short* wqT[2] = {(short*)scb, (short*)scb + (size_t)Dd * Dd};
    short* wkT[2] = {(short*)scb + 2 * (size_t)Dd * Dd,
                     (short*)scb + 3 * (size_t)Dd * Dd};

    // ---- setup ----
    const int DD = Dd * Dd;
    f2bf_k<<<dim3((2 * DD + 255) / 256), 256, 0, stream>>>(combW, combWb, 2 * DD);
    relpad_k<<<dim3(256 * Dd / 256), 256, 0, stream>>>(rel[0], relp[0]);
    relpad_k<<<dim3(256 * Dd / 256), 256, 0, stream>>>(rel[1], relp[1]);
    transpose_f2bf_k<<<dim3(16, 16), 256, 0, stream>>>(Wq[0], wqT[0]);
    transpose_f2bf_k<<<dim3(16, 16), 256, 0, stream>>>(Wq[1], wqT[1]);
    transpose_f2bf_k<<<dim3(16, 16), 256, 0, stream>>>(Wk[0], wkT[0]);
    transpose_f2bf_k<<<dim3(16, 16), 256, 0, stream>>>(Wk[1], wkT[1]);
    w2_k<<<dim3(128), 256, 0, stream>>>(wqT[0], wqT[1], wkT[0], wkT[1], waug);
    rw2_k<<<dim3(32), 256, 0, stream>>>(relp[0], relp[1], wqT[0], wqT[1], waug);
    uv_k<<<dim3(1024, 2, 2), 64, 0, stream>>>(wqT[0], wqT[1], wkT[0], wkT[1],
                                              bq[0], bq[1], bk[0], bk[1], waug);
    rb_k<<<dim3(130, 2), 64, 0, stream>>>(rel[0], rel[1], bq[0], bq[1],
                                          bk[0], bk[1], rbv);
    hidinit_k<<<dim3((int)(H / 256)), 256, 0, stream>>>(hid, hbuf[0][0], hbuf[1][0]);
    masks_k<<<dim3((BL + 255) / 256), 256, 0, stream>>>(spw, out2);

    int curb = 0;
    for (int t = 0; t < Tt; ++t) {
        short* h0 = hbuf[0][curb], *h1 = hbuf[1][curb];
        short* hn0 = hbuf[0][curb ^ 1], *hn1 = hbuf[1][curb ^ 1];
        gg_k<<<dim3(416), 512, 0, stream>>>(h0, h1, waug, combWb, g, x, yT);
        scores2_k<<<dim3(256), 256, 0, stream>>>(g, h0, h1, rbv, scb);
        softmax2_k<<<dim3(Lr, Bb, 2), 256, 0, stream>>>(scb, spw, out0, out1, probs, t);
        pv2_k<<<dim3(512), 256, 0, stream>>>(probs, yT, x, combB, hn0, hn1);
        curb ^= 1;
    }
}